// Round 13
// baseline (216.215 us; speedup 1.0000x reference)
//
#include <hip/hip_runtime.h>

typedef unsigned short u16;
typedef unsigned int   u32;
typedef __attribute__((ext_vector_type(8))) __bf16 bf8;
typedef __attribute__((ext_vector_type(4))) float  f4;
typedef __attribute__((ext_vector_type(8))) unsigned short us8;
typedef __attribute__((ext_vector_type(2))) unsigned int u32x2;

// ---------------- workspace layout (u16 element offsets) ----------------
#define XB_OFF    0L          // x bf16 [4096][1024]
#define BQ_OFF    4194304L    // 1024
#define BKV_OFF   4195328L    // 2048
#define BZ_OFF    4197376L    // 1024
#define WQT_OFF   4198400L    // Wq^T  [1024][1024]
#define WKVT_OFF  5246976L    // Wkv^T [2048][1024]
#define WZT_OFF   7344128L    // Wz^T  [1024][1024]
#define QB_OFF    8392704L    // Q(scaled by log2e/8)  [4096][1024]
#define KB_OFF    12587008L   // K  [4096][1024]
#define VB_OFF    16781312L   // V^T [1024][4096]
#define ZB_OFF    20975616L   // Z  [4096][1024] (attn output, gemm_out input)
#define FLAG_BYTE 50339840L   // u32 flag: 1 = fp32 inputs, 0 = bf16

#define CSC 0.18033688f       // log2(e) / sqrt(64), folded into Qb

__device__ __forceinline__ u16 f2bf(float f) {
  u32 u = __builtin_bit_cast(u32, f);
  return (u16)((u + 0x7FFFu + ((u >> 16) & 1u)) >> 16);  // RNE
}
__device__ __forceinline__ float bf2f(u16 v) {
  u32 u = ((u32)v) << 16;
  return __builtin_bit_cast(float, u);
}
__device__ __forceinline__ u32 fbits(float f) { return __builtin_bit_cast(u32, f); }
__device__ __forceinline__ void gl_lds16(const void* g, void* l) {
  __builtin_amdgcn_global_load_lds((__attribute__((address_space(1))) void*)g,
                                   (__attribute__((address_space(3))) void*)l,
                                   16, 0, 0);
}

// ---------------- prep: detect + normalize + all weight transposes ----------
__device__ __forceinline__ int detect_isf(const u32* xw, int tid, int* cnt) {
  if (tid == 0) *cnt = 0;
  __syncthreads();
  int c = 0;
  for (int i = 0; i < 4; ++i) {
    u32 w = xw[tid * 4 + i];
    u32 e = (w >> 7) & 0xFFu;
    c += (e >= 100u && e <= 140u) ? 1 : 0;
  }
  atomicAdd(cnt, c);
  __syncthreads();
  return (*cnt < 512) ? 1 : 0;
}

__device__ __forceinline__ void transpose_tile(
    const void* __restrict__ src, u16* __restrict__ dst,
    int R, int C, int rt, int ct, int isf, u16* tile)
{
  const int tid = threadIdx.x;
  for (int kk = 0; kk < 2; ++kk) {
    int cch = tid + (kk << 8);
    int r = cch >> 3, cc = cch & 7;
    us8 v;
    if (isf) {
      const f4* f = (const f4*)((const float*)src + (long)(rt + r) * C + ct + (cc << 3));
      f4 v0 = f[0], v1 = f[1];
      for (int i = 0; i < 4; ++i) { v[i] = f2bf(v0[i]); v[i + 4] = f2bf(v1[i]); }
    } else {
      v = *(const us8*)((const u16*)src + (long)(rt + r) * C + ct + (cc << 3));
    }
    *(us8*)&tile[r * 72 + (cc << 3)] = v;
  }
  __syncthreads();
  for (int kk = 0; kk < 2; ++kk) {
    int cch = tid + (kk << 8);
    int dd = cch >> 3, tc = cch & 7;
    us8 o;
    for (int i = 0; i < 8; ++i) o[i] = tile[(tc * 8 + i) * 72 + dd];
    *(us8*)&dst[(long)(ct + dd) * R + rt + (tc << 3)] = o;
  }
}

__global__ __launch_bounds__(256) void k_prep(
    const void* __restrict__ x, const void* __restrict__ bq,
    const void* __restrict__ bkv, const void* __restrict__ bz,
    const void* __restrict__ Wq, const void* __restrict__ Wkv, const void* __restrict__ Wz,
    u16* __restrict__ dst, u16* __restrict__ wqT, u16* __restrict__ wkvT, u16* __restrict__ wzT,
    u32* __restrict__ flag)
{
  __shared__ __align__(16) u16 tile[64 * 72];
  __shared__ int cnt;
  const int tid = threadIdx.x;
  const int isf = detect_isf((const u32*)x, tid, &cnt);
  const int bx = blockIdx.x;
  if (bx == 0 && tid == 0) *flag = (u32)isf;
  if (bx < 2050) {
    long base = (((long)bx << 8) + tid) << 3;
    const void* src; long off;
    if (base < 4194304L) {
      if (!isf) return;                 // bf16 inputs: qkv reads x directly
      src = x; off = base;
    }
    else if (base < 4195328L) { src = bq;  off = base - 4194304L; }
    else if (base < 4197376L) { src = bkv; off = base - 4195328L; }
    else                      { src = bz;  off = base - 4197376L; }
    us8 o;
    if (isf) {
      const f4* f = (const f4*)((const float*)src + off);
      f4 v0 = f[0], v1 = f[1];
      for (int i = 0; i < 4; ++i) { o[i] = f2bf(v0[i]); o[i + 4] = f2bf(v1[i]); }
    } else {
      o = *(const us8*)((const u16*)src + off);
    }
    *(us8*)&dst[base] = o;
  } else {
    int t = bx - 2050;            // 1024 blocks: 64 cx x 16 ry
    int cxa = t & 63, ry = t >> 6;
    const void* src; u16* dstw; int C, cx;
    if (cxa < 16)      { src = Wq;  dstw = wqT;  C = 1024; cx = cxa; }
    else if (cxa < 48) { src = Wkv; dstw = wkvT; C = 2048; cx = cxa - 16; }
    else               { src = Wz;  dstw = wzT;  C = 1024; cx = cxa - 48; }
    transpose_tile(src, dstw, 1024, C, ry << 6, cx << 6, isf, tile);
  }
}

// ---------------- 128x128 bf16 GEMM core (K=1024, BK=32) ----------
__device__ __forceinline__ void gemm128_mfma(const u16* __restrict__ Ablk,
                                             const u16* __restrict__ Btblk,
                                             f4 acc[4][4]) {
  __shared__ __align__(16) u16 As[4096];
  __shared__ __align__(16) u16 Bs[4096];
  const int tid = threadIdx.x;
  const int lane = tid & 63, w = tid >> 6;
  const int m15 = lane & 15, quad = lane >> 4;
  const int wm = (w >> 1) << 6, wn = (w & 1) << 6;
  for (int mt = 0; mt < 4; ++mt)
    for (int nt = 0; nt < 4; ++nt) acc[mt][nt] = (f4)(0.0f);
  for (int k0 = 0; k0 < 1024; k0 += 32) {
    for (int i = 0; i < 2; ++i) {
      int s = w * 2 + i;
      int L = s * 64 + lane;
      int r = L >> 2, c = L & 3;
      gl_lds16(&Ablk[(long)r * 1024 + k0 + c * 8], &As[s * 512]);
      gl_lds16(&Btblk[(long)r * 1024 + k0 + c * 8], &Bs[s * 512]);
    }
    __syncthreads();
    bf8 a[4], b[4];
    for (int mt = 0; mt < 4; ++mt) a[mt] = *(const bf8*)&As[(wm + mt * 16 + m15) * 32 + quad * 8];
    for (int nt = 0; nt < 4; ++nt) b[nt] = *(const bf8*)&Bs[(wn + nt * 16 + m15) * 32 + quad * 8];
    for (int mt = 0; mt < 4; ++mt)
      for (int nt = 0; nt < 4; ++nt)
        acc[mt][nt] = __builtin_amdgcn_mfma_f32_16x16x32_bf16(a[mt], b[nt], acc[mt][nt], 0, 0, 0);
    __syncthreads();
  }
}

// ---------------- 64x128 bf16 GEMM core (K=1024, BK=32) ----------
__device__ __forceinline__ void gemm64x128_mfma(const u16* __restrict__ Ablk,
                                                const u16* __restrict__ Btblk,
                                                f4 acc[2][4]) {
  __shared__ __align__(16) u16 As[2048];
  __shared__ __align__(16) u16 Bs[4096];
  const int tid = threadIdx.x;
  const int lane = tid & 63, w = tid >> 6;
  const int m15 = lane & 15, quad = lane >> 4;
  const int wm = (w >> 1) << 5, wn = (w & 1) << 6;
  for (int mt = 0; mt < 2; ++mt)
    for (int nt = 0; nt < 4; ++nt) acc[mt][nt] = (f4)(0.0f);
  for (int k0 = 0; k0 < 1024; k0 += 32) {
    {
      int L = w * 64 + lane;
      int r = L >> 2, c = L & 3;
      gl_lds16(&Ablk[(long)r * 1024 + k0 + c * 8], &As[w * 512]);
    }
    for (int i = 0; i < 2; ++i) {
      int s = w * 2 + i;
      int L = s * 64 + lane;
      int r = L >> 2, c = L & 3;
      gl_lds16(&Btblk[(long)r * 1024 + k0 + c * 8], &Bs[s * 512]);
    }
    __syncthreads();
    bf8 a[2], b[4];
    for (int mt = 0; mt < 2; ++mt) a[mt] = *(const bf8*)&As[(wm + mt * 16 + m15) * 32 + quad * 8];
    for (int nt = 0; nt < 4; ++nt) b[nt] = *(const bf8*)&Bs[(wn + nt * 16 + m15) * 32 + quad * 8];
    for (int mt = 0; mt < 2; ++mt)
      for (int nt = 0; nt < 4; ++nt)
        acc[mt][nt] = __builtin_amdgcn_mfma_f32_16x16x32_bf16(a[mt], b[nt], acc[mt][nt], 0, 0, 0);
    __syncthreads();
  }
}

// ---------------- fused QKV projection (XCD-swizzled 1-D grid, 768 blocks) --
__global__ __launch_bounds__(256) void k_gemm_qkv(
    const void* __restrict__ xraw, const u16* __restrict__ xb,
    const u16* __restrict__ WqT, const u16* __restrict__ WkvT,
    const u16* __restrict__ bqb, const u16* __restrict__ bkvb,
    u16* __restrict__ Qb, u16* __restrict__ Kb, u16* __restrict__ vtT,
    const u32* __restrict__ flag)
{
  __shared__ __align__(16) u16 vt[16384];   // [2 t-half][128 d][64 t], swizzled
  const u16* Asrc = (*flag) ? xb : (const u16*)xraw;   // bf16 inputs: no copy
  const int id = blockIdx.x;
  const int xcd = id & 7, j = id >> 3;          // j in [0,96)
  const int mtile = xcd * 4 + (j & 3);          // [0,32)
  const int ntile = j >> 2;                     // [0,24)
  const int nf = ntile << 7;
  const long bm = (long)(mtile << 7);
  const u16 *Bt, *bias; int ncol; float scale; int isV = 0;
  u16* Out;
  if (nf < 1024)      { Bt = WqT  + (long)nf * 1024;          bias = bqb  + nf;          Out = Qb;  ncol = nf;        scale = CSC; }
  else if (nf < 2048) { Bt = WkvT + (long)(nf - 1024) * 1024; bias = bkvb + (nf - 1024); Out = Kb;  ncol = nf - 1024; scale = 1.0f; }
  else                { Bt = WkvT + (long)(nf - 1024) * 1024; bias = bkvb + (nf - 1024); Out = vtT; ncol = nf - 2048; scale = 1.0f; isV = 1; }
  f4 acc[4][4];
  gemm128_mfma(Asrc + bm * 1024, Bt, acc);
  const int tid = threadIdx.x, lane = tid & 63, w = tid >> 6;
  const int m15 = lane & 15, quad = lane >> 4;
  const int wm = (w >> 1) << 6, wn = (w & 1) << 6;
  float bv[4];
  for (int nt = 0; nt < 4; ++nt) bv[nt] = bf2f(bias[wn + nt * 16 + m15]);
  if (!isV) {
    for (int mt = 0; mt < 4; ++mt)
      for (int nt = 0; nt < 4; ++nt)
        for (int jj = 0; jj < 4; ++jj) {
          long row = bm + wm + mt * 16 + quad * 4 + jj;
          int  col = ncol + wn + nt * 16 + m15;
          Out[row * 1024 + col] = f2bf((acc[mt][nt][jj] + bv[nt]) * scale);
        }
  } else {
    const int h2 = w >> 1;
    char* vbase = (char*)vt + h2 * 16384;
    for (int mt = 0; mt < 4; ++mt)
      for (int nt = 0; nt < 4; ++nt) {
        float f0 = acc[mt][nt][0] + bv[nt];
        float f1 = acc[mt][nt][1] + bv[nt];
        float f2 = acc[mt][nt][2] + bv[nt];
        float f3 = acc[mt][nt][3] + bv[nt];
        u32 p01 = __builtin_amdgcn_perm(fbits(f1) + 0x8000u, fbits(f0) + 0x8000u, 0x07060302u);
        u32 p23 = __builtin_amdgcn_perm(fbits(f3) + 0x8000u, fbits(f2) + 0x8000u, 0x07060302u);
        int d = wn + nt * 16 + m15;
        int dwb = mt * 8 + quad * 2;
        int phys = dwb ^ ((d & 7) << 2);
        u32x2 pk; pk[0] = p01; pk[1] = p23;
        *(u32x2*)(vbase + d * 128 + phys * 4) = pk;
      }
    __syncthreads();
    for (int it = 0; it < 8; ++it) {
      int idx = it * 256 + tid;
      int hh = idx >> 10, rem = idx & 1023;
      int d = rem >> 3, tc = rem & 7;
      int phys = (tc * 4) ^ ((d & 7) << 2);
      us8 v = *(us8*)((char*)vt + hh * 16384 + d * 128 + phys * 4);
      *(us8*)&Out[(long)(ncol + d) * 4096 + bm + hh * 64 + tc * 8] = v;
    }
  }
}

// ---------------- output projection (XCD-swizzled, plain epilogue) ----------
__global__ __launch_bounds__(256) void k_gemm_out(
    const u16* __restrict__ Zb, const u16* __restrict__ WzT, const u16* __restrict__ bzb,
    void* __restrict__ outp, const u32* __restrict__ flag)
{
  const int id = blockIdx.x;
  const int xcd = id & 7, j = id >> 3;          // j in [0,64)
  const int mtile = xcd * 8 + (j & 7);          // [0,64)
  const int ntile = j >> 3;                     // [0,8)
  const int nf = ntile << 7;
  const long bm = (long)(mtile << 6);
  f4 acc[2][4];
  gemm64x128_mfma(Zb + bm * 1024, WzT + (long)nf * 1024, acc);
  const int tid = threadIdx.x, lane = tid & 63, w = tid >> 6;
  const int m15 = lane & 15, quad = lane >> 4;
  const int wm = (w >> 1) << 5, wn = (w & 1) << 6;
  const int f32o = (int)*flag;
  float bv[4];
  for (int nt = 0; nt < 4; ++nt) bv[nt] = bf2f(bzb[nf + wn + nt * 16 + m15]);
  if (f32o) {
    float* O = (float*)outp;
    for (int mt = 0; mt < 2; ++mt)
      for (int nt = 0; nt < 4; ++nt)
        for (int jj = 0; jj < 4; ++jj) {
          long row = bm + wm + mt * 16 + quad * 4 + jj;
          int  col = nf + wn + nt * 16 + m15;
          O[row * 1024 + col] = acc[mt][nt][jj] + bv[nt];
        }
  } else {
    u16* O = (u16*)outp;
    for (int mt = 0; mt < 2; ++mt)
      for (int nt = 0; nt < 4; ++nt)
        for (int jj = 0; jj < 4; ++jj) {
          long row = bm + wm + mt * 16 + quad * 4 + jj;
          int  col = nf + wn + nt * 16 + m15;
          O[row * 1024 + col] = f2bf(acc[mt][nt][jj] + bv[nt]);
        }
  }
}

// ---------------- flash attention: 2q x 2kv wave split -----------------------
// 512 blocks: xcd owns 4 (b,h) pairs x 16 qt (K/V L2-local). Br=128, Bc=64.
// Waves: wq=w&1 (64 q-rows), wk=w>>1 (32-kv half). Per wave-kt: 12 b128 LDS
// reads (was 20 — K/V frags were 4x duplicated across waves). Additive no-max
// softmax makes the kv-split legal: partial O/Osum reduced once at the end
// through dead Ks/Vs LDS. P: [64 q][32 kv]/wave, swizzle keyed to row m15&3
// (writes 4 dw/bank = min, reads 8/bank = min). Osum via l = P @ ones (MFMA).
__global__ __launch_bounds__(256, 2) void k_attn(
    const u16* __restrict__ Qb, const u16* __restrict__ Kb, const u16* __restrict__ VtT,
    u16* __restrict__ Zb)
{
  __shared__ __align__(16) u16 Ks[8192];   // 2 buf x [2 plane][64 t][32 d]
  __shared__ __align__(16) u16 Vs[8192];   // 2 buf x [2 plane][64 d][32 t]
  __shared__ __align__(16) u16 Ps[8192];   // 4 waves x [64 q][32 kv] (swizzled)
  const int tid = threadIdx.x, lane = tid & 63, w = tid >> 6;
  const int m15 = lane & 15, quad = lane >> 4;
  const int wq = w & 1, wk = w >> 1;
  const int id = blockIdx.x;
  const int xcd = id & 7, j = id >> 3;     // j in [0,64)
  const int qt = j & 15;
  const int bh = xcd * 4 + (j >> 4);       // [0,32)
  const int h = bh & 15, b = bh >> 4;
  const long rowQ = (long)(b * 2048 + (qt << 7));

  const u16* Kp = &Kb[(long)(b * 2048) * 1024 + h * 64];
  const u16* Vp = &VtT[(long)(h * 64) * 4096 + b * 2048];

  const us8 ones_u = {0x3F80u, 0x3F80u, 0x3F80u, 0x3F80u, 0x3F80u, 0x3F80u, 0x3F80u, 0x3F80u};
  const bf8 vones = __builtin_bit_cast(bf8, ones_u);

  // Q B-fragments: 4 q-sets (this wave's 64 rows) x 2 d-planes
  bf8 aQ[4][2];
  for (int qs = 0; qs < 4; ++qs)
    for (int p = 0; p < 2; ++p)
      aQ[qs][p] = *(const bf8*)&Qb[(rowQ + wq * 64 + qs * 16 + m15) * 1024 + h * 64 + p * 32 + quad * 8];

  // stage kt=0 K/V into buffer 0 (all waves cooperate, unchanged layout)
  for (int i = 0; i < 2; ++i) {
    int s = w * 2 + i, L = s * 64 + lane;
    int p = L >> 8, r = (L >> 2) & 63, c = L & 3;
    gl_lds16(&Kp[(long)r * 1024 + p * 32 + c * 8], &Ks[s * 512]);
    gl_lds16(&Vp[(long)r * 4096 + p * 32 + c * 8], &Vs[s * 512]);
  }
  __syncthreads();

  u16* Pw = &Ps[w << 11];          // wave-private P: 64 rows x 64B
  const int c3 = m15 & 3;          // swizzle key (row-determined)

  f4 O[4][4], Osum[4];
  for (int qs = 0; qs < 4; ++qs) {
    Osum[qs] = (f4)(0.0f);
    for (int q = 0; q < 4; ++q) O[qs][q] = (f4)(0.0f);
  }

  for (int kt = 0; kt < 32; ++kt) {
    const int cur = (kt & 1) << 12;
    const int nxt = cur ^ 4096;
    const u16* Kn = Kp + 64 * 1024;
    const u16* Vn = Vp + 64;
    if (kt < 31) {
      for (int i = 0; i < 2; ++i) {
        int s = w * 2 + i, L = s * 64 + lane;
        int p = L >> 8, r = (L >> 2) & 63, c = L & 3;
        gl_lds16(&Kn[(long)r * 1024 + p * 32 + c * 8], &Ks[nxt + s * 512]);
        gl_lds16(&Vn[(long)r * 4096 + p * 32 + c * 8], &Vs[nxt + s * 512]);
      }
    }
    // S^T over this wave's 32-kv half (2 nt tiles), all 4 q-sets
    for (int ntl = 0; ntl < 2; ++ntl) {
      const int nt = wk * 2 + ntl;
      bf8 k0 = *(const bf8*)&Ks[cur + (nt * 16 + m15) * 32 + quad * 8];
      bf8 k1 = *(const bf8*)&Ks[cur + 2048 + (nt * 16 + m15) * 32 + quad * 8];
      for (int qs = 0; qs < 4; ++qs) {
        f4 S = (f4)(0.0f);
        S = __builtin_amdgcn_mfma_f32_16x16x32_bf16(k0, aQ[qs][0], S, 0, 0, 0);
        S = __builtin_amdgcn_mfma_f32_16x16x32_bf16(k1, aQ[qs][1], S, 0, 0, 0);
        float e0 = __builtin_amdgcn_exp2f(S[0]);
        float e1 = __builtin_amdgcn_exp2f(S[1]);
        float e2 = __builtin_amdgcn_exp2f(S[2]);
        float e3 = __builtin_amdgcn_exp2f(S[3]);
        u32 p01 = __builtin_amdgcn_perm(fbits(e1) + 0x8000u, fbits(e0) + 0x8000u, 0x07060302u);
        u32 p23 = __builtin_amdgcn_perm(fbits(e3) + 0x8000u, fbits(e2) + 0x8000u, 0x07060302u);
        u32x2 pk; pk[0] = p01; pk[1] = p23;
        // chunk = ntl*2 + (quad>>1); phys = chunk ^ c3; +8B if quad odd
        int phys = (ntl * 2 + (quad >> 1)) ^ c3;
        *(u32x2*)&Pw[((qs * 16 + m15) << 5) + (phys << 3) + ((quad & 1) << 2)] = pk;
      }
    }
    // O += P V over this wave's 32 kv; Osum += P @ ones
    {
      bf8 bv0 = *(const bf8*)&Vs[cur + wk * 2048 + (0 * 16 + m15) * 32 + quad * 8];
      bf8 bv1 = *(const bf8*)&Vs[cur + wk * 2048 + (1 * 16 + m15) * 32 + quad * 8];
      bf8 bv2 = *(const bf8*)&Vs[cur + wk * 2048 + (2 * 16 + m15) * 32 + quad * 8];
      bf8 bv3 = *(const bf8*)&Vs[cur + wk * 2048 + (3 * 16 + m15) * 32 + quad * 8];
      for (int qs = 0; qs < 4; ++qs) {
        int physr = quad ^ c3;
        bf8 ap = *(const bf8*)&Pw[((qs * 16 + m15) << 5) + (physr << 3)];
        O[qs][0] = __builtin_amdgcn_mfma_f32_16x16x32_bf16(ap, bv0, O[qs][0], 0, 0, 0);
        O[qs][1] = __builtin_amdgcn_mfma_f32_16x16x32_bf16(ap, bv1, O[qs][1], 0, 0, 0);
        O[qs][2] = __builtin_amdgcn_mfma_f32_16x16x32_bf16(ap, bv2, O[qs][2], 0, 0, 0);
        O[qs][3] = __builtin_amdgcn_mfma_f32_16x16x32_bf16(ap, bv3, O[qs][3], 0, 0, 0);
        Osum[qs] = __builtin_amdgcn_mfma_f32_16x16x32_bf16(ap, vones, Osum[qs], 0, 0, 0);
      }
    }
    Kp = Kn; Vp = Vn;
    __syncthreads();
  }
  // cross-wave kv reduction: wk=1 publishes O/Osum via dead Ks/Vs/Ps
  if (wk == 1) {
    float* buf  = (float*)(wq ? Vs : Ks);     // 16 KB each
    float* sbuf = (float*)Ps + wq * 1024;     // 4 KB each
    for (int qs = 0; qs < 4; ++qs) {
      *(f4*)(sbuf + qs * 256 + lane * 4) = Osum[qs];
      for (int dt = 0; dt < 4; ++dt)
        *(f4*)(buf + (qs * 4 + dt) * 256 + lane * 4) = O[qs][dt];
    }
  }
  __syncthreads();
  if (wk == 0) {
    float* buf  = (float*)(wq ? Vs : Ks);
    float* sbuf = (float*)Ps + wq * 1024;
    for (int qs = 0; qs < 4; ++qs) {
      Osum[qs] += *(const f4*)(sbuf + qs * 256 + lane * 4);
      for (int dt = 0; dt < 4; ++dt)
        O[qs][dt] += *(const f4*)(buf + (qs * 4 + dt) * 256 + lane * 4);
    }
    for (int qs = 0; qs < 4; ++qs)
      for (int jj = 0; jj < 4; ++jj) {
        float linv = 1.0f / Osum[qs][jj];
        long row = rowQ + wq * 64 + qs * 16 + quad * 4 + jj;
        for (int dt = 0; dt < 4; ++dt)
          Zb[row * 1024 + h * 64 + dt * 16 + m15] = f2bf(O[qs][dt][jj] * linv);
      }
  }
}

// ---------------- launch ----------------
extern "C" void kernel_launch(void* const* d_in, const int* in_sizes, int n_in,
                              void* d_out, int out_size, void* d_ws, size_t ws_size,
                              hipStream_t stream) {
  (void)in_sizes; (void)n_in; (void)out_size; (void)ws_size;
  const void* x   = d_in[0];
  const void* Wq  = d_in[2];
  const void* bq  = d_in[3];
  const void* Wkv = d_in[4];
  const void* bkv = d_in[5];
  const void* Wz  = d_in[6];
  const void* bz  = d_in[7];

  u16* ws   = (u16*)d_ws;
  u32* flag = (u32*)((char*)d_ws + FLAG_BYTE);
  u16* xb   = ws + XB_OFF;
  u16* bqb  = ws + BQ_OFF;
  u16* bkvb = ws + BKV_OFF;
  u16* bzb  = ws + BZ_OFF;
  u16* wqT  = ws + WQT_OFF;
  u16* wkvT = ws + WKVT_OFF;
  u16* wzT  = ws + WZT_OFF;
  u16* Qb   = ws + QB_OFF;
  u16* Kb   = ws + KB_OFF;
  u16* vtT  = ws + VB_OFF;
  u16* Zb   = ws + ZB_OFF;

  k_prep<<<dim3(3074), dim3(256), 0, stream>>>(x, bq, bkv, bz, Wq, Wkv, Wz,
                                               ws, wqT, wkvT, wzT, flag);
  k_gemm_qkv<<<dim3(768), dim3(256), 0, stream>>>(x, xb, wqT, wkvT, bqb, bkvb,
                                                  Qb, Kb, vtT, flag);
  k_attn<<<dim3(512), dim3(256), 0, stream>>>(Qb, Kb, vtT, Zb);
  k_gemm_out<<<dim3(512), dim3(256), 0, stream>>>(Zb, wzT, bzb, d_out, flag);
}